// Round 6
// baseline (334.020 us; speedup 1.0000x reference)
//
#include <hip/hip_runtime.h>
#include <hip/hip_bf16.h>

// Problem constants
#define BATCH 8
#define CCH   256
#define NPOS  4096
#define CQK   32

typedef __attribute__((ext_vector_type(8))) short short8;   // 8 bf16 = 4 VGPRs (MFMA A/B frag)
typedef __attribute__((ext_vector_type(4))) float f32x4;    // MFMA C/D frag

__device__ inline unsigned short f2b(float f) {
    __hip_bfloat16 h = __float2bfloat16(f);
    return *reinterpret_cast<unsigned short*>(&h);
}

__device__ inline short8 pack8(float4 a, float4 b) {
    short8 s;
    ((unsigned short*)&s)[0] = f2b(a.x);
    ((unsigned short*)&s)[1] = f2b(a.y);
    ((unsigned short*)&s)[2] = f2b(a.z);
    ((unsigned short*)&s)[3] = f2b(a.w);
    ((unsigned short*)&s)[4] = f2b(b.x);
    ((unsigned short*)&s)[5] = f2b(b.y);
    ((unsigned short*)&s)[6] = f2b(b.z);
    ((unsigned short*)&s)[7] = f2b(b.w);
    return s;
}

// Fragment-block layouts (as in prior rounds):
//   qb/kb: qk_addr — [b][n>>4][c>>3][n&15][c&7]  (c < 32)
//   vb:    v_addr  — [b][j>>5][c>>4][(j>>3)&3][c&15][j&7]
__device__ inline size_t qk_addr(int b, int n, int c) {
    return ((((size_t)b * 256 + (n >> 4)) * 4 + (c >> 3)) * 16 + (n & 15)) * 8 + (c & 7);
}
__device__ inline size_t v_addr(int b, int c, int j) {
    return (((((size_t)b * 128 + (j >> 5)) * 16 + (c >> 4)) * 4 + ((j >> 3) & 3)) * 16 + (c & 15)) * 8 + (j & 7);
}

// ---------------------------------------------------------------------------
// ONE persistent kernel: QKV projection -> grid barrier -> flash attention +
// output projection.  512 blocks x 256 threads, 2 blocks/CU guaranteed
// (launch_bounds(256,2), 38.1 KB LDS) -> all blocks co-resident, so the
// atomic grid barrier cannot deadlock.  Weight fragments are built directly
// from fp32 (same f2b rounding + MFMA chain order as the wsw path ->
// bit-identical outputs).  q stays in LDS (each block attends its own tile's
// rows); only K/V cross blocks via global.
// ---------------------------------------------------------------------------
__global__ __launch_bounds__(256, 2)
void fused_kernel(const float* __restrict__ x,
                  const float* __restrict__ Wq, const float* __restrict__ bq,
                  const float* __restrict__ Wk, const float* __restrict__ bk,
                  const float* __restrict__ Wv, const float* __restrict__ bv,
                  const float* __restrict__ Wf, const float* __restrict__ bfb,
                  unsigned short* __restrict__ kb, unsigned short* __restrict__ vb,
                  unsigned int* bar, float* __restrict__ out)
{
    // smem aliases: phase1 x-tile [256][66] bf16 (16896 sh) |
    //               phase2 P tiles [2][64][64] swz / O_n [64][264] (16896 sh)
    __shared__ __align__(16) unsigned short smem[16896];
    __shared__ __align__(16) unsigned short qlds[2048];   // q frags, this tile
    __shared__ float lred[64];

    const int bid  = blockIdx.x;
    const int b    = bid & 7;                 // XCD swizzle
    const int tile = bid >> 3;                // phase1 n-tile == phase2 i0/64
    const int t    = threadIdx.x;
    const int w    = t >> 6;
    const int lane = t & 63;
    const int q    = lane >> 4;
    const int ln   = lane & 15;
    const int lofs = (q * 16 + ln) * 8;

    // ===================== phase 1: QKV =====================
    {
        // ---- stage x tile [256c x 64n] -> bf16 LDS [c][n+2], coalesced ----
        const float* xb = x + ((size_t)b * 256) * 4096 + tile * 64;
        #pragma unroll
        for (int e = 0; e < 16; ++e) {
            const int g  = e * 256 + t;
            const int c  = g >> 4;
            const int n4 = (g & 15) * 4;
            float4 v = *(const float4*)(xb + (size_t)c * 4096 + n4);
            ushort4 s4 = {f2b(v.x), f2b(v.y), f2b(v.z), f2b(v.w)};
            *(ushort4*)&smem[c * 66 + n4] = s4;
        }
        // ---- q/k weight frags from fp32 (wave role: 0-1 q, 2-3 k) ----
        short8 wqk[8];
        const float* wsrc = ((w < 2) ? Wq : Wk)
                          + (size_t)((w & 1) * 16 + ln) * 256 + q * 8;
        #pragma unroll
        for (int kk = 0; kk < 8; ++kk)
            wqk[kk] = pack8(*(const float4*)(wsrc + kk * 32),
                            *(const float4*)(wsrc + kk * 32 + 4));
        const float* bias = (w < 2) ? bq : bk;
        const int cb16 = (w & 1) * 16;
        const float b0 = bias[cb16 + q * 4 + 0];
        const float b1 = bias[cb16 + q * 4 + 1];
        const float b2 = bias[cb16 + q * 4 + 2];
        const float b3 = bias[cb16 + q * 4 + 3];
        __syncthreads();

        #pragma unroll
        for (int oqh = 0; oqh < 2; ++oqh) {
            // ---- v weight frags (2 o-quads) from fp32, hoisted to regs ----
            short8 vwf[2][8];
            float  bvv[2];
            #pragma unroll
            for (int oq2 = 0; oq2 < 2; ++oq2) {
                const int row = w * 64 + (oqh * 2 + oq2) * 16 + ln;
                bvv[oq2] = bv[row];
                const float* vs = Wv + (size_t)row * 256 + q * 8;
                #pragma unroll
                for (int kk = 0; kk < 8; ++kk)
                    vwf[oq2][kk] = pack8(*(const float4*)(vs + kk * 32),
                                         *(const float4*)(vs + kk * 32 + 4));
            }
            #pragma unroll
            for (int it = 0; it < 4; ++it) {
                // ---- x^T fragment gather from LDS ----
                short8 xf[8];
                #pragma unroll
                for (int kk = 0; kk < 8; ++kk) {
                    short8 s;
                    #pragma unroll
                    for (int j = 0; j < 8; ++j)
                        ((unsigned short*)&s)[j] = smem[(kk * 32 + q * 8 + j) * 66 + it * 16 + ln];
                    xf[kk] = s;
                }
                if (oqh == 0) {
                    // ---- q/k: D[o-rows][n-cols] ----
                    f32x4 acc = {b0, b1, b2, b3};
                    #pragma unroll
                    for (int kk = 0; kk < 8; ++kk)
                        acc = __builtin_amdgcn_mfma_f32_16x16x32_bf16(wqk[kk], xf[kk], acc, 0, 0, 0);
                    ushort4 s = {f2b(acc[0]), f2b(acc[1]), f2b(acc[2]), f2b(acc[3])};
                    if (w < 2)
                        *(ushort4*)(qlds + qk_addr(0, it * 16 + ln, cb16 + q * 4)) = s;
                    else
                        *(ushort4*)(kb + qk_addr(b, tile * 64 + it * 16 + ln, cb16 + q * 4)) = s;
                }
                // ---- v: D[j-rows][c-cols] ----
                #pragma unroll
                for (int oq2 = 0; oq2 < 2; ++oq2) {
                    const int c = w * 64 + (oqh * 2 + oq2) * 16 + ln;
                    f32x4 acc = {bvv[oq2], bvv[oq2], bvv[oq2], bvv[oq2]};
                    #pragma unroll
                    for (int kk = 0; kk < 8; ++kk)
                        acc = __builtin_amdgcn_mfma_f32_16x16x32_bf16(xf[kk], vwf[oq2][kk], acc, 0, 0, 0);
                    ushort4 s = {f2b(acc[0]), f2b(acc[1]), f2b(acc[2]), f2b(acc[3])};
                    *(ushort4*)(vb + v_addr(b, c, tile * 64 + it * 16 + q * 4)) = s;
                }
            }
        }
    }

    // ===================== grid barrier =====================
    __threadfence();                           // release k/v (L2 writeback)
    __syncthreads();
    if (t == 0) {
        atomicAdd(bar, 1u);
        while (atomicAdd(bar, 0u) < 512u) __builtin_amdgcn_s_sleep(8);
    }
    __syncthreads();
    __threadfence();                           // acquire

    // ===================== phase 2: attention + projection =====================
    const int i0   = tile * 64;
    const unsigned pswz = (unsigned)((ln & 7) << 4);   // P-buffer XOR swizzle

    const short8 qfrag = *(const short8*)(qlds + (size_t)w * 512 + lofs);

    f32x4 acc[4][4];                             // [i-tile][c-chunk]
    #pragma unroll
    for (int it = 0; it < 4; ++it)
        #pragma unroll
        for (int cc = 0; cc < 4; ++cc) acc[it][cc] = (f32x4){0.f, 0.f, 0.f, 0.f};
    float accl = 0.f;                            // row-sum partial, i = w*16+ln

    const unsigned short* kbase = kb + (size_t)b * 256 * 512;
    const unsigned short* vbase = vb + (size_t)b * 128 * 8192;

    // ---- prologue: prefetch j0 = 0 fragments ----
    short8 kf[4], vf[4][2];
    #pragma unroll
    for (int jc = 0; jc < 4; ++jc)
        kf[jc] = *(const short8*)(kbase + (size_t)jc * 512 + lofs);
    #pragma unroll
    for (int cc = 0; cc < 4; ++cc) {
        vf[cc][0] = *(const short8*)(vbase + (w * 4 + cc) * 512 + lofs);
        vf[cc][1] = *(const short8*)(vbase + 8192 + (w * 4 + cc) * 512 + lofs);
    }

    int pb = 0;
    for (int j0 = 0; j0 < 4096; j0 += 64, pb ^= 1) {
        // ---- issue next iteration's K/V loads first (wrap at the end) ----
        const int jn = (j0 + 64) & 4095;
        short8 kf_n[4], vf_n[4][2];
        #pragma unroll
        for (int jc = 0; jc < 4; ++jc)
            kf_n[jc] = *(const short8*)(kbase + ((size_t)((jn >> 4) + jc) * 512) + lofs);
        const unsigned short* vt_n = vbase + (size_t)(jn >> 5) * 8192;
        #pragma unroll
        for (int cc = 0; cc < 4; ++cc) {
            vf_n[cc][0] = *(const short8*)(vt_n + (w * 4 + cc) * 512 + lofs);
            vf_n[cc][1] = *(const short8*)(vt_n + 8192 + (w * 4 + cc) * 512 + lofs);
        }
        // ---- S^T via swapped operands: lane holds S[i=w*16+ln][j=jc*16+quad*4+r] ----
        f32x4 st[4];
        #pragma unroll
        for (int jc = 0; jc < 4; ++jc)
            st[jc] = __builtin_amdgcn_mfma_f32_16x16x32_bf16(kf[jc], qfrag,
                      (f32x4){0.f, 0.f, 0.f, 0.f}, 0, 0, 0);
        // ---- P = exp(S); row sum; vectorized swizzled P writes ----
        #pragma unroll
        for (int jc = 0; jc < 4; ++jc) {
            float p0 = __expf(st[jc][0]);
            float p1 = __expf(st[jc][1]);
            float p2 = __expf(st[jc][2]);
            float p3 = __expf(st[jc][3]);
            accl += (p0 + p1) + (p2 + p3);
            ushort4 pk = {f2b(p0), f2b(p1), f2b(p2), f2b(p3)};
            unsigned byt = (((unsigned)(pb * 64 + w * 16 + ln)) << 7)
                         + ((jc * 32 + q * 8) ^ pswz);
            *(ushort4*)((unsigned char*)smem + byt) = pk;
        }
        __syncthreads();
        // ---- O += P V with resident V : 32 MFMAs ----
        #pragma unroll
        for (int it = 0; it < 4; ++it) {
            const unsigned rowb = ((unsigned)(pb * 64 + it * 16 + ln)) << 7;
            const short8 pf0 = *(const short8*)((const unsigned char*)smem
                                 + rowb + ((q * 16) ^ pswz));
            const short8 pf1 = *(const short8*)((const unsigned char*)smem
                                 + rowb + ((64 + q * 16) ^ pswz));
            #pragma unroll
            for (int cc = 0; cc < 4; ++cc) {
                acc[it][cc] = __builtin_amdgcn_mfma_f32_16x16x32_bf16(pf0, vf[cc][0], acc[it][cc], 0, 0, 0);
                acc[it][cc] = __builtin_amdgcn_mfma_f32_16x16x32_bf16(pf1, vf[cc][1], acc[it][cc], 0, 0, 0);
            }
        }
        // ---- rotate prefetched fragments ----
        #pragma unroll
        for (int jc = 0; jc < 4; ++jc) kf[jc] = kf_n[jc];
        #pragma unroll
        for (int cc = 0; cc < 4; ++cc) {
            vf[cc][0] = vf_n[cc][0];
            vf[cc][1] = vf_n[cc][1];
        }
    }

    // ---- row sums: reduce quads (i = w*16+ln) ----
    {
        float v = accl;
        v += __shfl_xor(v, 16, 64);
        v += __shfl_xor(v, 32, 64);
        if (lane < 16) lred[w * 16 + lane] = v;
    }
    __syncthreads();   // also orders: last P reads before O_n overwrites smem

    // ---- epilogue A: normalize O, write bf16 to LDS [i][c] (stride 264) ----
    #pragma unroll
    for (int it = 0; it < 4; ++it) {
        float linv[4];
        #pragma unroll
        for (int r = 0; r < 4; ++r) linv[r] = 1.f / lred[it * 16 + q * 4 + r];
        #pragma unroll
        for (int cc = 0; cc < 4; ++cc) {
            const int c = w * 64 + cc * 16 + ln;
            #pragma unroll
            for (int r = 0; r < 4; ++r)
                smem[((size_t)(it * 16 + q * 4 + r)) * 264 + c] = f2b(acc[it][cc][r] * linv[r]);
        }
    }
    __syncthreads();

    // ---- epilogue B: out = Wf * O_n + bf; Wf frags built from fp32 ----
    #pragma unroll
    for (int oq = 0; oq < 4; ++oq) {
        const int o = w * 64 + oq * 16 + ln;
        short8 wff[8];
        const float* fs = Wf + (size_t)o * 256 + q * 8;
        #pragma unroll
        for (int kk = 0; kk < 8; ++kk)
            wff[kk] = pack8(*(const float4*)(fs + kk * 32),
                            *(const float4*)(fs + kk * 32 + 4));
        const float bias = bfb[o];
        #pragma unroll
        for (int it = 0; it < 4; ++it) {
            short8 af[8];
            #pragma unroll
            for (int kk = 0; kk < 8; ++kk)
                af[kk] = *(const short8*)&smem[((size_t)(it * 16 + ln)) * 264 + kk * 32 + q * 8];
            f32x4 pa = {0.f, 0.f, 0.f, 0.f};
            #pragma unroll
            for (int kk = 0; kk < 8; ++kk)
                pa = __builtin_amdgcn_mfma_f32_16x16x32_bf16(af[kk], wff[kk], pa, 0, 0, 0);
            float4 s = {pa[0] + bias, pa[1] + bias, pa[2] + bias, pa[3] + bias};
            *(float4*)(out + (size_t)(b * 256 + o) * 4096 + i0 + it * 16 + q * 4) = s;
        }
    }
}

// ---------------------------------------------------------------------------
extern "C" void kernel_launch(void* const* d_in, const int* in_sizes, int n_in,
                              void* d_out, int out_size, void* d_ws, size_t ws_size,
                              hipStream_t stream)
{
    const float* x  = (const float*)d_in[0];
    const float* Wq = (const float*)d_in[1];
    const float* bq = (const float*)d_in[2];
    const float* Wk = (const float*)d_in[3];
    const float* bk = (const float*)d_in[4];
    const float* Wv = (const float*)d_in[5];
    const float* bv = (const float*)d_in[6];
    const float* Wf = (const float*)d_in[7];
    const float* bf = (const float*)d_in[8];
    float* out = (float*)d_out;

    // workspace: barrier counter (zeroed per launch) + kb + vb
    unsigned int*   bar = (unsigned int*)d_ws;
    unsigned short* kb  = (unsigned short*)d_ws + 64;             // 8*4096*32 shorts
    unsigned short* vb  = kb + (size_t)BATCH * NPOS * CQK;        // 8*256*4096 shorts

    hipMemsetAsync(bar, 0, 8, stream);
    fused_kernel<<<512, 256, 0, stream>>>(x, Wq, bq, Wk, bk, Wv, bv, Wf, bf,
                                          kb, vb, bar, out);
}

// Round 8
// 213.085 us; speedup vs baseline: 1.5675x; 1.5675x over previous
//
#include <hip/hip_runtime.h>
#include <hip/hip_bf16.h>

// Problem constants
#define BATCH 8
#define CCH   256
#define NPOS  4096
#define CQK   32
#define LOG2E 1.4426950408889634f

typedef __attribute__((ext_vector_type(8))) short short8;   // 8 bf16 = 4 VGPRs (MFMA A/B frag)
typedef __attribute__((ext_vector_type(4))) float f32x4;    // MFMA C/D frag

__device__ inline unsigned short f2b(float f) {
    __hip_bfloat16 h = __float2bfloat16(f);
    return *reinterpret_cast<unsigned short*>(&h);
}

// ---------------------------------------------------------------------------
// Fragment-block swizzled layouts.  A 512-short block holds one 16x32 MFMA
// operand tile; lane (q=quad, ln) reads short8 at block*512 + (q*16+ln)*8.
//   qb/kb: qk_addr  — [b][n>>4][c>>3][n&15][c&7]           (c < 32)
//   vb:     v_addr  — [b][j>>5][c>>4][(j>>3)&3][c&15][j&7]
//   wsw:    wsw_addr — og-unit = 16 rows x 256 c; og: q=0..1,k=2..3,v=4..19,f=20..35
// ---------------------------------------------------------------------------
__device__ inline size_t qk_addr(int b, int n, int c) {
    return ((((size_t)b * 256 + (n >> 4)) * 4 + (c >> 3)) * 16 + (n & 15)) * 8 + (c & 7);
}
__device__ inline size_t v_addr(int b, int c, int j) {
    return (((((size_t)b * 128 + (j >> 5)) * 16 + (c >> 4)) * 4 + ((j >> 3) & 3)) * 16 + (c & 15)) * 8 + (j & 7);
}
__device__ inline size_t wsw_addr(int og, int c, int ol) {
    return ((size_t)(og * 8 + (c >> 5))) * 512 + (((c >> 3) & 3) * 16 + ol) * 8 + (c & 7);
}

// ---------------------------------------------------------------------------
// Kernel 0: prep_w — weights fp32 -> wsw bf16 fragment layout.
// Wk (og 2..3) pre-scaled by log2(e) so attn can use exp2f directly
// (v_exp_f32 computes 2^x; saves the x*log2e multiply per exp).
// ---------------------------------------------------------------------------
__global__ __launch_bounds__(256, 4)
void prep_w_kernel(const float* __restrict__ Wq, const float* __restrict__ Wk,
                   const float* __restrict__ Wv, const float* __restrict__ Wf,
                   unsigned short* __restrict__ wsw)
{
    const int og = blockIdx.x;           // 0..35
    const int t  = threadIdx.x;
    const float* src; int orow; float scl = 1.f;
    if (og < 2)       { src = Wq; orow = og * 16; }
    else if (og < 4)  { src = Wk; orow = (og - 2) * 16; scl = LOG2E; }
    else if (og < 20) { src = Wv; orow = (og - 4) * 16; }
    else              { src = Wf; orow = (og - 20) * 16; }
    #pragma unroll
    for (int e = 0; e < 16; ++e) {
        int idx = t + e * 256;
        int ol = idx >> 8, c = idx & 255;
        wsw[wsw_addr(og, c, ol)] = f2b(src[(orow + ol) * 256 + c] * scl);
    }
}

// ---------------------------------------------------------------------------
// Kernel 1: fused transpose + QKV projection (R4 structure, unchanged except
// bk bias scaled by log2e to match the pre-scaled Wk).
// ---------------------------------------------------------------------------
__global__ __launch_bounds__(512, 2)
void qkv_kernel(const float* __restrict__ x,
                const unsigned short* __restrict__ wsw,
                const float* __restrict__ bq, const float* __restrict__ bk,
                const float* __restrict__ bv,
                unsigned short* __restrict__ qb, unsigned short* __restrict__ kb,
                unsigned short* __restrict__ vb)
{
    __shared__ __align__(16) unsigned short xl[64 * 280];   // [n][c pad 280] = 35840 B

    const int nt   = blockIdx.x;          // 64 position tiles
    const int b    = blockIdx.y;
    const int t    = threadIdx.x;         // 0..511
    const int w    = t >> 6;              // 0..7
    const int lane = t & 63;
    const int q    = lane >> 4;
    const int ln   = lane & 15;
    const int lofs = (q * 16 + ln) * 8;
    const int wq   = w & 3;               // role: 0-1 q, 2-3 k (+ v og chunk)
    const int ith  = w >> 2;              // it-half

    // ---- stage x tile [256c x 64n] -> bf16 LDS transposed [n][c] ----
    {
        const int c  = t & 255;
        const int nb = (t >> 8) * 4;
        const float* xb = x + ((size_t)(b * 256 + c)) * 4096 + nt * 64;
        #pragma unroll
        for (int e = 0; e < 8; ++e) {
            const int n = nb + e * 8;
            float4 v = *(const float4*)(xb + n);
            xl[(n + 0) * 280 + c] = f2b(v.x);
            xl[(n + 1) * 280 + c] = f2b(v.y);
            xl[(n + 2) * 280 + c] = f2b(v.z);
            xl[(n + 3) * 280 + c] = f2b(v.w);
        }
    }
    __syncthreads();

    // ---- q/k weight fragments (og = wq) + bias (k side scaled by log2e) ----
    short8 wqk[8];
    #pragma unroll
    for (int kk = 0; kk < 8; ++kk)
        wqk[kk] = *(const short8*)(wsw + (size_t)(wq * 8 + kk) * 512 + lofs);
    const float* bias = (wq < 2) ? bq : bk;
    const float ksc = (wq < 2) ? 1.f : LOG2E;
    const int cb16 = (wq & 1) * 16;
    const float b0 = bias[cb16 + q * 4 + 0] * ksc;
    const float b1 = bias[cb16 + q * 4 + 1] * ksc;
    const float b2 = bias[cb16 + q * 4 + 2] * ksc;
    const float b3 = bias[cb16 + q * 4 + 3] * ksc;
    unsigned short* dst = (wq < 2) ? qb : kb;

    #pragma unroll
    for (int itl = 0; itl < 2; ++itl) {
        const int it = ith * 2 + itl;
        short8 xf[8];
        #pragma unroll
        for (int kk = 0; kk < 8; ++kk)
            xf[kk] = *(const short8*)&xl[(it * 16 + ln) * 280 + kk * 32 + q * 8];

        // ---- q/k: D[o-rows][n-cols] ----
        {
            f32x4 acc = {b0, b1, b2, b3};
            #pragma unroll
            for (int kk = 0; kk < 8; ++kk)
                acc = __builtin_amdgcn_mfma_f32_16x16x32_bf16(wqk[kk], xf[kk], acc, 0, 0, 0);
            ushort4 s = {f2b(acc[0]), f2b(acc[1]), f2b(acc[2]), f2b(acc[3])};
            *(ushort4*)(dst + qk_addr(b, nt * 64 + it * 16 + ln, cb16 + q * 4)) = s;
        }

        // ---- v: D[j-rows][c-cols], o-chunk wq*64 ----
        #pragma unroll
        for (int oq = 0; oq < 4; ++oq) {
            const int c  = wq * 64 + oq * 16 + ln;
            const float bb = bv[c];
            f32x4 acc = {bb, bb, bb, bb};
            const int og = 4 + wq * 4 + oq;
            #pragma unroll
            for (int kk = 0; kk < 8; ++kk) {
                short8 bfr = *(const short8*)(wsw + (size_t)(og * 8 + kk) * 512 + lofs);
                acc = __builtin_amdgcn_mfma_f32_16x16x32_bf16(xf[kk], bfr, acc, 0, 0, 0);
            }
            ushort4 s = {f2b(acc[0]), f2b(acc[1]), f2b(acc[2]), f2b(acc[3])};
            *(ushort4*)(vb + v_addr(b, c, nt * 64 + it * 16 + q * 4)) = s;
        }
    }
}

// ---------------------------------------------------------------------------
// Kernel 2: fused flash attention + output projection — R8 pipelined.
// R5's loop phase-alternated (exp VALU burst | barrier | PV MFMA burst ->
// MfmaUtil 32%, VALUBusy 40%, neither pipe fed continuously).  Now each
// inter-barrier region holds BOTH PV(j) (MFMA, reads P[pb]+V(j)) and
// QK^T(j+1)+exp2 (VALU, writes P[pb^1]) — independent streams on opposite
// P buffers, so the scheduler interleaves exp under the MFMA burst.
// K/V double-buffered in regs (prefetch depth 1 iter > L2 latency).
// exp2f direct (Wk/bk pre-scaled by log2e).  setprio(1) around MFMA cluster.
// ---------------------------------------------------------------------------
__global__ __launch_bounds__(256, 2)
void attn_kernel(const unsigned short* __restrict__ qb,
                 const unsigned short* __restrict__ kb,
                 const unsigned short* __restrict__ vb,
                 const unsigned short* __restrict__ wsw,
                 const float* __restrict__ bfb, float* __restrict__ out)
{
    // shbuf aliases: main loop P tiles [2][64][64] swizzled (32768 B),
    //                epilogue O_n      [64][264]            (33792 B)
    __shared__ __align__(16) unsigned short shbuf[64 * 264];
    __shared__ float lred[64];

    const int bid  = blockIdx.x;
    const int b    = bid & 7;                    // XCD swizzle
    const int i0   = (bid >> 3) * 64;
    const int t    = threadIdx.x;
    const int w    = t >> 6;
    const int lane = t & 63;
    const int quad = lane >> 4;
    const int ln   = lane & 15;

    const int ibase = i0 + w * 16;
    const int lofs  = (quad * 16 + ln) * 8;
    const unsigned pswz = (unsigned)((ln & 7) << 4);   // P-buffer XOR swizzle

    const short8 qfrag = *(const short8*)(qb + (((size_t)b * 256 + (ibase >> 4)) * 512) + lofs);

    f32x4 acc[4][4];                             // [i-tile][c-chunk]
    #pragma unroll
    for (int it = 0; it < 4; ++it)
        #pragma unroll
        for (int cc = 0; cc < 4; ++cc) acc[it][cc] = (f32x4){0.f, 0.f, 0.f, 0.f};
    float accl = 0.f;                            // row-sum partial, i = w*16+ln

    const unsigned short* kbase = kb + (size_t)b * 256 * 512;
    const unsigned short* vbase = vb + (size_t)b * 128 * 8192;

    // ---- prologue: K(0)->kfC, V(0)->vfA, K(64)->kfB; S(0); exp2; P[0] ----
    short8 kfB[4], kfC[4], vfA[4][2], vfB[4][2];
    #pragma unroll
    for (int jc = 0; jc < 4; ++jc)
        kfC[jc] = *(const short8*)(kbase + (size_t)jc * 512 + lofs);
    #pragma unroll
    for (int cc = 0; cc < 4; ++cc) {
        vfA[cc][0] = *(const short8*)(vbase + (w * 4 + cc) * 512 + lofs);
        vfA[cc][1] = *(const short8*)(vbase + 8192 + (w * 4 + cc) * 512 + lofs);
    }
    #pragma unroll
    for (int jc = 0; jc < 4; ++jc)
        kfB[jc] = *(const short8*)(kbase + (size_t)(4 + jc) * 512 + lofs);

    #pragma unroll
    for (int jc = 0; jc < 4; ++jc) {
        f32x4 st = __builtin_amdgcn_mfma_f32_16x16x32_bf16(kfC[jc], qfrag,
                    (f32x4){0.f, 0.f, 0.f, 0.f}, 0, 0, 0);
        float p0 = exp2f(st[0]);
        float p1 = exp2f(st[1]);
        float p2 = exp2f(st[2]);
        float p3 = exp2f(st[3]);
        accl += (p0 + p1) + (p2 + p3);
        ushort4 pk = {f2b(p0), f2b(p1), f2b(p2), f2b(p3)};
        unsigned byt = (((unsigned)(w * 16 + ln)) << 7)
                     + ((jc * 32 + quad * 8) ^ pswz);
        *(ushort4*)((unsigned char*)shbuf + byt) = pk;
    }
    __syncthreads();

    int pb = 0;
    // 63 pipelined iterations: PV(j0) || S/exp2(j0+64)
    for (int j0 = 0; j0 < 4032; j0 += 64, pb ^= 1) {
        const int jn1 = j0 + 64;
        const int jn2 = (j0 + 128) & 4095;
        // ---- issue next loads: V(jn1)->vfB, K(jn2)->kfC ----
        const unsigned short* vt = vbase + (size_t)(jn1 >> 5) * 8192;
        #pragma unroll
        for (int cc = 0; cc < 4; ++cc) {
            vfB[cc][0] = *(const short8*)(vt + (w * 4 + cc) * 512 + lofs);
            vfB[cc][1] = *(const short8*)(vt + 8192 + (w * 4 + cc) * 512 + lofs);
        }
        #pragma unroll
        for (int jc = 0; jc < 4; ++jc)
            kfC[jc] = *(const short8*)(kbase + ((size_t)((jn2 >> 4) + jc) * 512) + lofs);

        __builtin_amdgcn_s_setprio(1);
        // ---- S^T(jn1) with resident kfB ----
        f32x4 stB[4];
        #pragma unroll
        for (int jc = 0; jc < 4; ++jc)
            stB[jc] = __builtin_amdgcn_mfma_f32_16x16x32_bf16(kfB[jc], qfrag,
                       (f32x4){0.f, 0.f, 0.f, 0.f}, 0, 0, 0);
        // ---- PV(j0): P[pb] + vfA : 32 MFMAs (independent of stB/exp) ----
        #pragma unroll
        for (int it = 0; it < 4; ++it) {
            const unsigned rowb = ((unsigned)(pb * 64 + it * 16 + ln)) << 7;
            const short8 pf0 = *(const short8*)((const unsigned char*)shbuf
                                 + rowb + ((quad * 16) ^ pswz));
            const short8 pf1 = *(const short8*)((const unsigned char*)shbuf
                                 + rowb + ((64 + quad * 16) ^ pswz));
            #pragma unroll
            for (int cc = 0; cc < 4; ++cc) {
                acc[it][cc] = __builtin_amdgcn_mfma_f32_16x16x32_bf16(pf0, vfA[cc][0], acc[it][cc], 0, 0, 0);
                acc[it][cc] = __builtin_amdgcn_mfma_f32_16x16x32_bf16(pf1, vfA[cc][1], acc[it][cc], 0, 0, 0);
            }
        }
        __builtin_amdgcn_s_setprio(0);
        // ---- exp2(jn1) -> P[pb^1] (opposite buffer; overlaps PV above) ----
        #pragma unroll
        for (int jc = 0; jc < 4; ++jc) {
            float p0 = exp2f(stB[jc][0]);
            float p1 = exp2f(stB[jc][1]);
            float p2 = exp2f(stB[jc][2]);
            float p3 = exp2f(stB[jc][3]);
            accl += (p0 + p1) + (p2 + p3);
            ushort4 pk = {f2b(p0), f2b(p1), f2b(p2), f2b(p3)};
            unsigned byt = (((unsigned)((pb ^ 1) * 64 + w * 16 + ln)) << 7)
                         + ((jc * 32 + quad * 8) ^ pswz);
            *(ushort4*)((unsigned char*)shbuf + byt) = pk;
        }
        __syncthreads();
        // ---- rotate double buffers ----
        #pragma unroll
        for (int jc = 0; jc < 4; ++jc) kfB[jc] = kfC[jc];
        #pragma unroll
        for (int cc = 0; cc < 4; ++cc) {
            vfA[cc][0] = vfB[cc][0];
            vfA[cc][1] = vfB[cc][1];
        }
    }

    // ---- epilogue PV(4032): P[pb] + vfA ----
    #pragma unroll
    for (int it = 0; it < 4; ++it) {
        const unsigned rowb = ((unsigned)(pb * 64 + it * 16 + ln)) << 7;
        const short8 pf0 = *(const short8*)((const unsigned char*)shbuf
                             + rowb + ((quad * 16) ^ pswz));
        const short8 pf1 = *(const short8*)((const unsigned char*)shbuf
                             + rowb + ((64 + quad * 16) ^ pswz));
        #pragma unroll
        for (int cc = 0; cc < 4; ++cc) {
            acc[it][cc] = __builtin_amdgcn_mfma_f32_16x16x32_bf16(pf0, vfA[cc][0], acc[it][cc], 0, 0, 0);
            acc[it][cc] = __builtin_amdgcn_mfma_f32_16x16x32_bf16(pf1, vfA[cc][1], acc[it][cc], 0, 0, 0);
        }
    }

    // ---- row sums: reduce quads (i = w*16+ln) ----
    {
        float v = accl;
        v += __shfl_xor(v, 16, 64);
        v += __shfl_xor(v, 32, 64);
        if (lane < 16) lred[w * 16 + lane] = v;
    }
    __syncthreads();   // also orders: last P reads before O_n overwrites shbuf

    // ---- epilogue A: normalize O, write bf16 to LDS [i][c] (stride 264) ----
    #pragma unroll
    for (int it = 0; it < 4; ++it) {
        float linv[4];
        #pragma unroll
        for (int r = 0; r < 4; ++r) linv[r] = 1.f / lred[it * 16 + quad * 4 + r];
        #pragma unroll
        for (int cc = 0; cc < 4; ++cc) {
            const int c = w * 64 + cc * 16 + ln;
            #pragma unroll
            for (int r = 0; r < 4; ++r)
                shbuf[((size_t)(it * 16 + quad * 4 + r)) * 264 + c] = f2b(acc[it][cc][r] * linv[r]);
        }
    }
    __syncthreads();

    // ---- epilogue B: out = Wf * O_n + bf, each wave owns o-chunk w*64 ----
    #pragma unroll
    for (int it = 0; it < 4; ++it) {
        short8 af[8];
        #pragma unroll
        for (int kk = 0; kk < 8; ++kk)
            af[kk] = *(const short8*)&shbuf[((size_t)(it * 16 + ln)) * 264 + kk * 32 + quad * 8];
        #pragma unroll
        for (int oq = 0; oq < 4; ++oq) {
            const int o  = w * 64 + oq * 16 + ln;
            const int og = 20 + w * 4 + oq;
            f32x4 pa = {0.f, 0.f, 0.f, 0.f};
            #pragma unroll
            for (int kk = 0; kk < 8; ++kk) {
                short8 bfr = *(const short8*)(wsw + (size_t)(og * 8 + kk) * 512 + lofs);
                pa = __builtin_amdgcn_mfma_f32_16x16x32_bf16(af[kk], bfr, pa, 0, 0, 0);
            }
            const float bias = bfb[o];
            float4 s = {pa[0] + bias, pa[1] + bias, pa[2] + bias, pa[3] + bias};
            *(float4*)(out + (size_t)(b * 256 + o) * 4096 + i0 + it * 16 + quad * 4) = s;
        }
    }
}

// ---------------------------------------------------------------------------
extern "C" void kernel_launch(void* const* d_in, const int* in_sizes, int n_in,
                              void* d_out, int out_size, void* d_ws, size_t ws_size,
                              hipStream_t stream)
{
    const float* x  = (const float*)d_in[0];
    const float* Wq = (const float*)d_in[1];
    const float* bq = (const float*)d_in[2];
    const float* Wk = (const float*)d_in[3];
    const float* bk = (const float*)d_in[4];
    const float* Wv = (const float*)d_in[5];
    const float* bv = (const float*)d_in[6];
    const float* Wf = (const float*)d_in[7];
    const float* bf = (const float*)d_in[8];
    float* out = (float*)d_out;

    // workspace (shorts): qb, kb, vb, wsw
    unsigned short* qb  = (unsigned short*)d_ws;                  // 8*4096*32
    unsigned short* kb  = qb + (size_t)BATCH * NPOS * CQK;
    unsigned short* vb  = kb + (size_t)BATCH * NPOS * CQK;        // 8*256*4096
    unsigned short* wsw = vb + (size_t)BATCH * CCH * NPOS;        // 36*8*512

    prep_w_kernel<<<36, 256, 0, stream>>>(Wq, Wk, Wv, Wf, wsw);
    qkv_kernel<<<dim3(64, 8), 512, 0, stream>>>(x, wsw, bq, bk, bv, qb, kb, vb);
    attn_kernel<<<512, 256, 0, stream>>>(qb, kb, vb, wsw, bf, out);
}